// Round 8
// baseline (56.003 us; speedup 1.0000x reference)
//
#include <hip/hip_runtime.h>
#include <math.h>

#define Bn 32
#define Ln 524288
#define NF 4

#define TPB   512               // threads per WG (8 waves)
#define CPT   20                // samples per thread (5 float4 -> odd slot stride)
#define S_WG  (TPB * CPT)       // 10240 samples staged per WG
#define OUT   8192              // output samples per WG
#define WU    (S_WG - OUT)      // 2048 warm-up samples
#define SLOT  (S_WG / 4)        // 2560 float4 slots
#define OSLOT (OUT / 4)         // 2048
#define WSLOT (WU / 4)          // 512
#define TPR   (Ln / OUT)        // 64 tiles per row
#define NT    (Bn * TPR)        // 2048 WGs

// ws layout (float indices) — nothing inter-WG.
#define COEF_OFF 0               // 20 floats
#define POWJ_OFF 64              // j=0..5: A^(20*2^j)  (384 floats)
#define XW1_OFF  448             // A^1280 (wave span)  (64 floats)

// LDS layout (float indices). No padding/swizzle: per-thread slot stride is 5
// (odd) so b128 reads/writes are naturally bank-conflict-free.
#define WAGG_L (SLOT * 4)        // 8 waves * 8
#define PA_L   (WAGG_L + 64)     // 8 waves * 8
#define LDS_F  (PA_L + 64)       // 10368 floats = 41.5 KB -> 3 WG/CU

// ---------------------------------------------------------------------------
// Precompute (1 block, 64 thr): f32-rounded coefs; A^20 via unit-state sim
// (double); squaring chain A^(20*2^j) j=0..5 and XW1 = A^1280.
// A and its powers are block-lower-triangular (cascade: filter f depends only
// on filters <= f), upper blocks exactly zero.
// ---------------------------------------------------------------------------
__global__ void precompute_k(const float* __restrict__ lr,
                             const float* __restrict__ ra,
                             const float* __restrict__ b0,
                             const float* __restrict__ b1,
                             const float* __restrict__ b2,
                             float* __restrict__ ws) {
    __shared__ double Md[64], Td[64];
    const int t = threadIdx.x;

    if (t < NF) {
        double r   = 0.999 / (1.0 + exp(-(double)lr[t]));
        double ang = 3.14159265358979323846 / (1.0 + exp(-(double)ra[t]));
        ws[COEF_OFF + t * 5 + 0] = b0[t];
        ws[COEF_OFF + t * 5 + 1] = b1[t];
        ws[COEF_OFF + t * 5 + 2] = b2[t];
        ws[COEF_OFF + t * 5 + 3] = (float)(-2.0 * r * cos(ang));
        ws[COEF_OFF + t * 5 + 4] = (float)(r * r);
    }
    __syncthreads();

    if (t < 8) {
        double cb0[NF], cb1[NF], cb2[NF], ca1[NF], ca2[NF];
        for (int f = 0; f < NF; ++f) {
            cb0[f] = (double)ws[COEF_OFF + f * 5 + 0];
            cb1[f] = (double)ws[COEF_OFF + f * 5 + 1];
            cb2[f] = (double)ws[COEF_OFF + f * 5 + 2];
            ca1[f] = (double)ws[COEF_OFF + f * 5 + 3];
            ca2[f] = (double)ws[COEF_OFF + f * 5 + 4];
        }
        double s[8];
        for (int r = 0; r < 8; ++r) s[r] = 0.0;
        s[t] = 1.0;
        for (int n = 0; n < CPT; ++n) {
            double v = 0.0;
            for (int f = 0; f < NF; ++f) {
                double y     = cb0[f] * v + s[2 * f];
                s[2 * f]     = cb1[f] * v - ca1[f] * y + s[2 * f + 1];
                s[2 * f + 1] = cb2[f] * v - ca2[f] * y;
                v = y;
            }
        }
        for (int r = 0; r < 8; ++r) Md[r * 8 + t] = s[r];  // column t of A^20
    }
    __syncthreads();

    ws[POWJ_OFF + t] = (float)Md[t];  // j=0: A^20
    const int r8 = t >> 3, c8 = t & 7;
    for (int sq = 1; sq <= 6; ++sq) {
        double acc = 0.0;
        for (int m = 0; m < 8; ++m) acc += Md[r8 * 8 + m] * Md[m * 8 + c8];
        Td[t] = acc;
        __syncthreads();
        Md[t] = Td[t];
        __syncthreads();
        if (sq <= 5) ws[POWJ_OFF + sq * 64 + t] = (float)Md[t];  // A^(20*2^sq)
        else         ws[XW1_OFF + t]            = (float)Md[t];  // A^1280
    }
}

// ---------------------------------------------------------------------------
__device__ __forceinline__ void step1(float& u, float* s,
                                      const float* c0, const float* c1,
                                      const float* c2, const float* A1,
                                      const float* A2) {
#pragma unroll
    for (int f = 0; f < NF; ++f) {
        float yv     = fmaf(c0[f], u, s[2 * f]);
        s[2 * f]     = fmaf(-A1[f], yv, fmaf(c1[f], u, s[2 * f + 1]));
        s[2 * f + 1] = fmaf(-A2[f], yv, c2[f] * u);
        u = yv;
    }
}

// Sparse (block-lower-triangular) 8x8 matvec; T is wave-uniform (global ws)
// so elements fold to scalar loads. Row r uses columns 0..(r|1): 40 fma.
__device__ __forceinline__ void matvec_acc_sp(float* o, const float* __restrict__ T,
                                              const float* p) {
#pragma unroll
    for (int r = 0; r < 8; ++r) {
        const int ncol = (r | 1) + 1;
#pragma unroll
        for (int c = 0; c < 8; ++c)
            if (c < ncol) o[r] = fmaf(T[r * 8 + c], p[c], o[r]);
    }
}
__device__ __forceinline__ void matvec_rep_sp(float* h, const float* __restrict__ T) {
    float tmp[8];
#pragma unroll
    for (int r = 0; r < 8; ++r) {
        const int ncol = (r | 1) + 1;
        float acc = 0.f;
#pragma unroll
        for (int c = 0; c < 8; ++c)
            if (c < ncol) acc = fmaf(T[r * 8 + c], h[c], acc);
        tmp[r] = acc;
    }
#pragma unroll
    for (int r = 0; r < 8; ++r) h[r] = tmp[r];
}

// ---------------------------------------------------------------------------
// One WG = one 8192-sample output tile + 2048-sample warm-up prefix.
// No inter-WG communication. x held in VGPRs between the two passes.
// ---------------------------------------------------------------------------
__global__ __launch_bounds__(TPB, 6) void biquad_k(const float* __restrict__ x,
                                                   const float* __restrict__ ws,
                                                   float* __restrict__ y) {
    __shared__ __align__(16) float ldsf[LDS_F];
    float4* lds4 = (float4*)ldsf;
    const int t    = threadIdx.x;
    const int lane = t & 63;
    const int w    = t >> 6;

    const int tile = blockIdx.x;
    const int row  = tile / TPR;
    const int tpos = tile % TPR;

    const float* __restrict__ mats = ws + POWJ_OFF;  // wave-uniform -> scalar
    const float* __restrict__ xw1  = ws + XW1_OFF;

    // stage x -> LDS (coalesced reads, identity slots). Tile-0 warm-up = zeros.
    const long gbase = (long)row * (Ln / 4) + (long)tpos * OSLOT - WSLOT;
    const float4* xg4 = (const float4*)x;
#pragma unroll
    for (int j = 0; j < SLOT / TPB; ++j) {  // 5
        const int n = j * TPB + t;
        float4 v = make_float4(0.f, 0.f, 0.f, 0.f);
        if (tpos > 0 || n >= WSLOT) v = xg4[gbase + n];
        lds4[n] = v;
    }

    float c0[NF], c1[NF], c2[NF], A1[NF], A2[NF];
#pragma unroll
    for (int f = 0; f < NF; ++f) {
        c0[f] = ws[COEF_OFF + f * 5 + 0];
        c1[f] = ws[COEF_OFF + f * 5 + 1];
        c2[f] = ws[COEF_OFF + f * 5 + 2];
        A1[f] = ws[COEF_OFF + f * 5 + 3];
        A2[f] = ws[COEF_OFF + f * 5 + 4];
    }
    __syncthreads();

    // LDS -> regs once (odd stride 5 => conflict-free); keep for both passes
    float4 xr[CPT / 4];
#pragma unroll
    for (int i = 0; i < CPT / 4; ++i) xr[i] = lds4[t * (CPT / 4) + i];

    // zero-state pass over own 20-sample chunk
    float s[8];
#pragma unroll
    for (int r = 0; r < 8; ++r) s[r] = 0.f;
#pragma unroll
    for (int i = 0; i < CPT / 4; ++i) {
        float q[4] = {xr[i].x, xr[i].y, xr[i].z, xr[i].w};
#pragma unroll
        for (int e = 0; e < 4; ++e) { float u = q[e]; step1(u, s, c0, c1, c2, A1, A2); }
    }

    // intra-wave affine Kogge-Stone over 64 chunks (registers + shfl)
    float v8[8];
#pragma unroll
    for (int r = 0; r < 8; ++r) v8[r] = s[r];
#pragma unroll
    for (int j = 0; j < 6; ++j) {
        const int st = 1 << j;
        float p[8];
#pragma unroll
        for (int r = 0; r < 8; ++r) p[r] = __shfl_up(v8[r], st, 64);
        if (lane >= st) matvec_acc_sp(v8, mats + j * 64, p);
    }

    // wave aggregates -> LDS
    if (lane == 63) {
#pragma unroll
        for (int r = 0; r < 8; ++r) ldsf[WAGG_L + w * 8 + r] = v8[r];
    }
    __syncthreads();

    // cross-wave prefix, oldest-first Horner with XW1 = A^1280:
    //   s_enter(w) = XW1*s_enter(w-1) + W_{w-1}
    if (w == 0 && lane < 8) {
        float acc[8];
#pragma unroll
        for (int r = 0; r < 8; ++r) acc[r] = 0.f;
        for (int m = 0; m < lane; ++m) {
            matvec_rep_sp(acc, xw1);
#pragma unroll
            for (int r = 0; r < 8; ++r) acc[r] += ldsf[WAGG_L + m * 8 + r];
        }
#pragma unroll
        for (int r = 0; r < 8; ++r) ldsf[PA_L + lane * 8 + r] = acc[r];
    }
    __syncthreads();

    // entry(t) = A^(20*lane) * H_w + v8_{lane-1}
    float H[8];
#pragma unroll
    for (int r = 0; r < 8; ++r) H[r] = ldsf[PA_L + w * 8 + r];
#pragma unroll
    for (int j = 0; j < 6; ++j) {
        if (lane & (1 << j)) matvec_rep_sp(H, mats + j * 64);
    }
    float pv[8];
#pragma unroll
    for (int r = 0; r < 8; ++r) pv[r] = __shfl_up(v8[r], 1, 64);
#pragma unroll
    for (int r = 0; r < 8; ++r) s[r] = H[r] + ((lane > 0) ? pv[r] : 0.f);

    // final pass from exact entry state (x from regs); y -> own LDS slots
#pragma unroll
    for (int i = 0; i < CPT / 4; ++i) {
        float q[4] = {xr[i].x, xr[i].y, xr[i].z, xr[i].w};
#pragma unroll
        for (int e = 0; e < 4; ++e) { float u = q[e]; step1(u, s, c0, c1, c2, A1, A2); q[e] = u; }
        lds4[t * (CPT / 4) + i] = make_float4(q[0], q[1], q[2], q[3]);
    }
    __syncthreads();

    // coalesced write of the output region (slots >= WSLOT)
    float4* yg4 = (float4*)y;
    const long obase = (long)row * (Ln / 4) + (long)tpos * OSLOT;
#pragma unroll
    for (int j = 0; j < OSLOT / TPB; ++j) {  // 4
        const int n = WSLOT + j * TPB + t;
        yg4[obase + (n - WSLOT)] = lds4[n];
    }
}

// ---------------------------------------------------------------------------
extern "C" void kernel_launch(void* const* d_in, const int* in_sizes, int n_in,
                              void* d_out, int out_size, void* d_ws, size_t ws_size,
                              hipStream_t stream) {
    const float* x  = (const float*)d_in[0];
    const float* lr = (const float*)d_in[1];
    const float* ra = (const float*)d_in[2];
    const float* b0 = (const float*)d_in[3];
    const float* b1 = (const float*)d_in[4];
    const float* b2 = (const float*)d_in[5];
    float* y  = (float*)d_out;
    float* ws = (float*)d_ws;

    precompute_k<<<dim3(1), dim3(64), 0, stream>>>(lr, ra, b0, b1, b2, ws);
    biquad_k<<<dim3(NT), dim3(TPB), 0, stream>>>(x, ws, y);
}